// Round 4
// baseline (67.821 us; speedup 1.0000x reference)
//
#include <hip/hip_runtime.h>
#include <hip/hip_bf16.h>
#include <math.h>

// CBOW negative-sampling loss, collapsed:
//   out = -( (1/B) * sum_b [ logsig(dot(emb_w[target[b]], c_b))
//                          + sum_k logsig(dot(emb_w[noise[b,k]], c_b)) ] )
//   c_b = mean_w ctx_w[context[b,w]]
// V=100000, D=128, B=16384, W=10, K=10.
//
// R4: back to the R2 partitioning (16 lanes/row, 4 rows/wave — R3's 32-lane
// variant regressed), plus R3's vector index loads + 32-bit gather offsets,
// plus fused final reduction (last-block-done; saves a kernel launch + gap).

#define CBOW_B 16384
#define CBOW_W 10
#define CBOW_K 10
#define CBOW_D 128
#define ROWS_PER_BLOCK 16
#define NBLOCKS (CBOW_B / ROWS_PER_BLOCK)   // 1024

__device__ __forceinline__ float log_sigmoid(float x) {
    const float t = __expf(-fabsf(x));
    return fminf(x, 0.0f) - __logf(1.0f + t);
}

__global__ __launch_bounds__(256) void cbow_fused(
    const int* __restrict__ context,   // [B, W]
    const int* __restrict__ target,    // [B]
    const int* __restrict__ noise,     // [B, K]
    const float* __restrict__ emb_w,   // [V, D]
    const float* __restrict__ ctx_w,   // [V, D]
    float* __restrict__ block_sums,    // [NBLOCKS] in d_ws
    int* __restrict__ done_count,      // [1] in d_ws, zeroed per call
    float* __restrict__ out)           // [1]
{
    const int wave = threadIdx.x >> 6;  // 0..3
    const int lane = threadIdx.x & 63;
    const int grp  = lane >> 4;         // 0..3: batch row within wave
    const int sub  = lane & 15;         // lane within 16-lane group
    const int b = blockIdx.x * ROWS_PER_BLOCK + wave * 4 + grp;
    const unsigned elem = sub * 8u;     // floats [elem, elem+8) of D=128

    // ---- vector index loads (40 B rows are 8 B aligned -> int2) ----
    const int2* cI = reinterpret_cast<const int2*>(&context[b * CBOW_W]);
    const int2 c01 = cI[0], c23 = cI[1], c45 = cI[2], c67 = cI[3], c89 = cI[4];
    const int2* nI = reinterpret_cast<const int2*>(&noise[b * CBOW_K]);
    const int2 n01 = nI[0], n23 = nI[1], n45 = nI[2], n67 = nI[3], n89 = nI[4];
    const int tgt = target[b];

    // ---- context mean-pool (8 floats/lane); 32-bit gather offsets ----
    float c0x=0,c0y=0,c0z=0,c0w=0, c1x=0,c1y=0,c1z=0,c1w=0;
    #define CBOW_ACC(IDX) {                                                    \
        const float4* p = reinterpret_cast<const float4*>(                     \
            ctx_w + (((unsigned)(IDX) << 7) + elem));                          \
        const float4 r0 = p[0];                                                \
        const float4 r1 = p[1];                                                \
        c0x += r0.x; c0y += r0.y; c0z += r0.z; c0w += r0.w;                    \
        c1x += r1.x; c1y += r1.y; c1z += r1.z; c1w += r1.w; }
    CBOW_ACC(c01.x) CBOW_ACC(c01.y) CBOW_ACC(c23.x) CBOW_ACC(c23.y)
    CBOW_ACC(c45.x) CBOW_ACC(c45.y) CBOW_ACC(c67.x) CBOW_ACC(c67.y)
    CBOW_ACC(c89.x) CBOW_ACC(c89.y)
    #undef CBOW_ACC
    const float inv = 1.0f / CBOW_W;
    c0x*=inv; c0y*=inv; c0z*=inv; c0w*=inv;
    c1x*=inv; c1y*=inv; c1z*=inv; c1w*=inv;

    // ---- positive + negative scores ----
    float sum = 0.0f;
    #define CBOW_DOT(IDX) {                                                    \
        const float4* p = reinterpret_cast<const float4*>(                     \
            emb_w + (((unsigned)(IDX) << 7) + elem));                          \
        const float4 r0 = p[0];                                                \
        const float4 r1 = p[1];                                                \
        float d = c0x*r0.x + c0y*r0.y + c0z*r0.z + c0w*r0.w                    \
                + c1x*r1.x + c1y*r1.y + c1z*r1.z + c1w*r1.w;                   \
        d += __shfl_xor(d, 1, 64);                                             \
        d += __shfl_xor(d, 2, 64);                                             \
        d += __shfl_xor(d, 4, 64);                                             \
        d += __shfl_xor(d, 8, 64);                                             \
        sum += log_sigmoid(d); }
    CBOW_DOT(tgt)
    CBOW_DOT(n01.x) CBOW_DOT(n01.y) CBOW_DOT(n23.x) CBOW_DOT(n23.y)
    CBOW_DOT(n45.x) CBOW_DOT(n45.y) CBOW_DOT(n67.x) CBOW_DOT(n67.y)
    CBOW_DOT(n89.x) CBOW_DOT(n89.y)
    #undef CBOW_DOT

    // ---- combine the 4 groups of this wave ----
    sum += __shfl_xor(sum, 16, 64);
    sum += __shfl_xor(sum, 32, 64);     // every lane holds the wave total

    // ---- per-block partial, then last-block-done final reduce ----
    __shared__ float wsum[4];
    __shared__ int is_last;
    if (lane == 0) wsum[wave] = sum;
    __syncthreads();
    if (threadIdx.x == 0) {
        block_sums[blockIdx.x] = wsum[0] + wsum[1] + wsum[2] + wsum[3];
        __threadfence();                             // partial visible device-wide
        const int old = atomicAdd(done_count, 1);    // device-scope
        is_last = (old == NBLOCKS - 1);
    }
    __syncthreads();
    if (!is_last) return;

    __threadfence();                                 // acquire all partials
    __shared__ double sh[256];
    double s = 0.0;
    for (int i = threadIdx.x; i < NBLOCKS; i += 256)
        s += (double)block_sums[i];                  // fixed order -> deterministic
    sh[threadIdx.x] = s;
    __syncthreads();
    #pragma unroll
    for (int stride = 128; stride >= 1; stride >>= 1) {
        if (threadIdx.x < stride) sh[threadIdx.x] += sh[threadIdx.x + stride];
        __syncthreads();
    }
    if (threadIdx.x == 0) {
        out[0] = (float)(-sh[0] / (double)CBOW_B);
    }
}

extern "C" void kernel_launch(void* const* d_in, const int* in_sizes, int n_in,
                              void* d_out, int out_size, void* d_ws, size_t ws_size,
                              hipStream_t stream) {
    const int*   context = (const int*)d_in[0];   // [B, W]
    const int*   target  = (const int*)d_in[1];   // [B]
    const int*   noise   = (const int*)d_in[2];   // [B, K]
    const float* emb_w   = (const float*)d_in[3]; // [V, D]
    const float* ctx_w   = (const float*)d_in[4]; // [V, D]
    float*       out     = (float*)d_out;
    float*       block_sums = (float*)d_ws;                 // NBLOCKS floats
    int*         done_count = (int*)d_ws + NBLOCKS;         // 1 int

    hipMemsetAsync(done_count, 0, sizeof(int), stream);     // graph-capture-legal
    cbow_fused<<<NBLOCKS, 256, 0, stream>>>(context, target, noise, emb_w, ctx_w,
                                            block_sums, done_count, out);
}

// Round 5
// 33.564 us; speedup vs baseline: 2.0206x; 2.0206x over previous
//
#include <hip/hip_runtime.h>
#include <hip/hip_bf16.h>
#include <math.h>

// CBOW negative-sampling loss, collapsed:
//   out = -( (1/B) * sum_b [ logsig(dot(emb_w[target[b]], c_b))
//                          + sum_k logsig(dot(emb_w[noise[b,k]], c_b)) ] )
//   c_b = mean_w ctx_w[context[b,w]]
// V=100000, D=128, B=16384, W=10, K=10.
//
// R5: R2 structure (16 lanes/row, 4 rows/wave, two kernels — the R4 fused
// last-block-done regressed 2x: per-block device-scope __threadfence = L2
// writeback x1024, stalling the gather-serving L2s). New here:
//  - __launch_bounds__(256,4): allow ~128 VGPR. Grid gives only 16 waves/CU
//    anyway, so deep per-thread load pipelining is free.
//  - explicit prefetch phases: 10 ctx rows then 11 emb rows into registers,
//    loads independent -> ~10 gathers in flight/thread (R2: VGPR32 => ~2-3).
//  - all 11 shuffle-reduce butterflies run concurrently (independent chains)
//    instead of serial per-dot chains.
//  - int2 index loads, 32-bit shift addressing (kept from R3/R4).

#define CBOW_B 16384
#define CBOW_W 10
#define CBOW_K 10
#define CBOW_D 128
#define ROWS_PER_BLOCK 16
#define NBLOCKS (CBOW_B / ROWS_PER_BLOCK)   // 1024
#define NDOT (CBOW_K + 1)                   // 11

__device__ __forceinline__ float log_sigmoid(float x) {
    const float t = __expf(-fabsf(x));
    return fminf(x, 0.0f) - __logf(1.0f + t);
}

__global__ __launch_bounds__(256, 4) void cbow_main(
    const int* __restrict__ context,   // [B, W]
    const int* __restrict__ target,    // [B]
    const int* __restrict__ noise,     // [B, K]
    const float* __restrict__ emb_w,   // [V, D]
    const float* __restrict__ ctx_w,   // [V, D]
    float* __restrict__ block_sums)    // [NBLOCKS]
{
    const int wave = threadIdx.x >> 6;  // 0..3
    const int lane = threadIdx.x & 63;
    const int grp  = lane >> 4;         // 0..3: batch row within wave
    const int sub  = lane & 15;         // lane within 16-lane group
    const int b = blockIdx.x * ROWS_PER_BLOCK + wave * 4 + grp;
    const unsigned elem = sub * 8u;     // floats [elem, elem+8) of D=128

    // ---- vector index loads (40 B rows are 8 B aligned -> int2) ----
    const int2* cI = reinterpret_cast<const int2*>(&context[b * CBOW_W]);
    const int2 c01 = cI[0], c23 = cI[1], c45 = cI[2], c67 = cI[3], c89 = cI[4];
    const int2* nI = reinterpret_cast<const int2*>(&noise[b * CBOW_K]);
    const int2 n01 = nI[0], n23 = nI[1], n45 = nI[2], n67 = nI[3], n89 = nI[4];

    int cidx[CBOW_W] = { c01.x, c01.y, c23.x, c23.y, c45.x, c45.y,
                         c67.x, c67.y, c89.x, c89.y };
    int didx[NDOT]   = { target[b], n01.x, n01.y, n23.x, n23.y, n45.x, n45.y,
                         n67.x, n67.y, n89.x, n89.y };

    // ---- phase 1: prefetch all 10 ctx rows, then accumulate ----
    float4 a0[CBOW_W], a1[CBOW_W];
    #pragma unroll
    for (int w = 0; w < CBOW_W; ++w) {
        const float4* p = reinterpret_cast<const float4*>(
            ctx_w + (((unsigned)cidx[w] << 7) + elem));
        a0[w] = p[0];
        a1[w] = p[1];
    }
    float c0x=0,c0y=0,c0z=0,c0w=0, c1x=0,c1y=0,c1z=0,c1w=0;
    #pragma unroll
    for (int w = 0; w < CBOW_W; ++w) {
        c0x += a0[w].x; c0y += a0[w].y; c0z += a0[w].z; c0w += a0[w].w;
        c1x += a1[w].x; c1y += a1[w].y; c1z += a1[w].z; c1w += a1[w].w;
    }
    const float inv = 1.0f / CBOW_W;
    c0x*=inv; c0y*=inv; c0z*=inv; c0w*=inv;
    c1x*=inv; c1y*=inv; c1z*=inv; c1w*=inv;

    // ---- phase 2: prefetch all 11 emb rows, compute partials ----
    float part[NDOT];
    {
        float4 e0[NDOT], e1[NDOT];
        #pragma unroll
        for (int k = 0; k < NDOT; ++k) {
            const float4* p = reinterpret_cast<const float4*>(
                emb_w + (((unsigned)didx[k] << 7) + elem));
            e0[k] = p[0];
            e1[k] = p[1];
        }
        #pragma unroll
        for (int k = 0; k < NDOT; ++k) {
            part[k] = c0x*e0[k].x + c0y*e0[k].y + c0z*e0[k].z + c0w*e0[k].w
                    + c1x*e1[k].x + c1y*e1[k].y + c1z*e1[k].z + c1w*e1[k].w;
        }
    }

    // ---- phase 3: 11 independent 4-step butterflies (chains overlap) ----
    #pragma unroll
    for (int m = 1; m <= 8; m <<= 1) {
        #pragma unroll
        for (int k = 0; k < NDOT; ++k) part[k] += __shfl_xor(part[k], m, 64);
    }

    // ---- phase 4: logsig + row sum ----
    float sum = 0.0f;
    #pragma unroll
    for (int k = 0; k < NDOT; ++k) sum += log_sigmoid(part[k]);

    // ---- combine the 4 groups of this wave ----
    sum += __shfl_xor(sum, 16, 64);
    sum += __shfl_xor(sum, 32, 64);     // every lane holds the wave total

    // ---- per-block partial sum (deterministic; no atomics) ----
    __shared__ float wsum[4];
    if (lane == 0) wsum[wave] = sum;
    __syncthreads();
    if (threadIdx.x == 0) {
        block_sums[blockIdx.x] = wsum[0] + wsum[1] + wsum[2] + wsum[3];
    }
}

__global__ __launch_bounds__(256) void cbow_finish(
    const float* __restrict__ block_sums, float* __restrict__ out)
{
    __shared__ double sh[256];
    double s = 0.0;
    for (int i = threadIdx.x; i < NBLOCKS; i += 256) s += (double)block_sums[i];
    sh[threadIdx.x] = s;
    __syncthreads();
    #pragma unroll
    for (int stride = 128; stride >= 1; stride >>= 1) {
        if (threadIdx.x < stride) sh[threadIdx.x] += sh[threadIdx.x + stride];
        __syncthreads();
    }
    if (threadIdx.x == 0) {
        out[0] = (float)(-sh[0] / (double)CBOW_B);
    }
}

extern "C" void kernel_launch(void* const* d_in, const int* in_sizes, int n_in,
                              void* d_out, int out_size, void* d_ws, size_t ws_size,
                              hipStream_t stream) {
    const int*   context = (const int*)d_in[0];   // [B, W]
    const int*   target  = (const int*)d_in[1];   // [B]
    const int*   noise   = (const int*)d_in[2];   // [B, K]
    const float* emb_w   = (const float*)d_in[3]; // [V, D]
    const float* ctx_w   = (const float*)d_in[4]; // [V, D]
    float*       out     = (float*)d_out;
    float*       block_sums = (float*)d_ws;       // NBLOCKS floats = 4 KiB

    cbow_main<<<NBLOCKS, 256, 0, stream>>>(context, target, noise, emb_w, ctx_w,
                                           block_sums);
    cbow_finish<<<1, 256, 0, stream>>>(block_sums, out);
}